// Round 3
// baseline (1073.696 us; speedup 1.0000x reference)
//
#include <hip/hip_runtime.h>

// RNN: h_t = relu(x_t @ W_ih^T + b_ih + b_hh + h_{t-1} @ W_hh^T); y_t = h_t @ W_out^T + b_out
// B=512, T=2000, D=3, H=50.
// R3: v_readlane is throughput-limited (~9 cyc each, measured via R1/R2 linear scaling)
// -> eliminate it. Broadcast h via LDS: lane i writes h_i (ds_write_b32), all lanes
// read the full vector back as 12x ds_read_b128 + 1x ds_read_b64 at the SAME address
// (native broadcast, conflict-free). DS ops from one wave complete in order -> no
// barrier needed in a single-wave block. x broadcast via per-tile staged LDS buffer
// (1 b128 read/step), next tile's x prefetched into registers under the step loop.
// One batch per wave, 512 blocks = 2 waves/CU.

#define BB 512
#define TT 2000
#define DD 3
#define HH 50
#define TILE 50      // divides TT exactly (40 tiles)
#define HSTR 51      // odd stride -> conflict-free transpose column reads

__global__ __launch_bounds__(64) void rnn_fused_kernel(
    const float* __restrict__ x,      // [B,T,D]
    const float* __restrict__ W_ih,   // [H,D]
    const float* __restrict__ W_hh,   // [H,H]
    const float* __restrict__ b_ih,   // [H]
    const float* __restrict__ b_hh,   // [H]
    const float* __restrict__ W_out,  // [D,H]
    const float* __restrict__ b_out,  // [D]
    float* __restrict__ out)          // [B,T,D]
{
    const int lane = threadIdx.x;                  // 0..63
    const int b    = blockIdx.x;                   // one batch element per wave
    const int row  = (lane < HH) ? lane : (HH - 1);

    // Per-lane weights: row `row` of W_hh, W_ih row, combined bias.
    float w[HH];
    #pragma unroll
    for (int j = 0; j < HH; ++j) w[j] = W_hh[row * HH + j];
    const float wi0 = W_ih[row * DD + 0];
    const float wi1 = W_ih[row * DD + 1];
    const float wi2 = W_ih[row * DD + 2];
    const float bias = b_ih[row] + b_hh[row];

    // Wave-uniform addresses -> compiler emits s_load; held in SGPRs.
    const float bo0 = b_out[0];
    const float bo1 = b_out[1];
    const float bo2 = b_out[2];

    __shared__ __align__(16) float hbuf[64];          // staged h (broadcast source)
    __shared__ __align__(16) float xbuf[TILE * 4];    // x triples, padded to float4
    __shared__ __align__(16) float hsT[64 * HSTR];    // h transpose for output proj
    __shared__ __align__(16) float woT[HH * 4];       // {wo0,wo1,wo2,pad} per hidden i

    if (lane < HH) {
        float4 wv;
        wv.x = W_out[0 * HH + lane];
        wv.y = W_out[1 * HH + lane];
        wv.z = W_out[2 * HH + lane];
        wv.w = 0.0f;
        ((float4*)woT)[lane] = wv;
    }

    const float* xb = x   + (size_t)b * TT * DD;
    float*       yb = out + (size_t)b * TT * DD;

    // Preload tile 0's x into registers.
    float nxa = 0.0f, nxb = 0.0f, nxc = 0.0f;
    if (lane < TILE) {
        const float* xs = xb + (size_t)lane * DD;
        nxa = xs[0]; nxb = xs[1]; nxc = xs[2];
    }

    float h = 0.0f;

    for (int tile = 0; tile < TT / TILE; ++tile) {
        const int t0 = tile * TILE;

        // Commit staged x registers for this tile to LDS.
        if (lane < TILE) {
            float4 xq; xq.x = nxa; xq.y = nxb; xq.z = nxc; xq.w = 0.0f;
            ((float4*)xbuf)[lane] = xq;
        }
        // Prefetch next tile's x into registers (latency hides under 50 steps).
        if (tile + 1 < TT / TILE && lane < TILE) {
            const float* xs = xb + (size_t)(t0 + TILE + lane) * DD;
            nxa = xs[0]; nxb = xs[1]; nxc = xs[2];
        }

        #pragma unroll 2
        for (int s = 0; s < TILE; ++s) {
            // x triple for this step: same-address b128 read -> broadcast.
            float4 xq = ((const float4*)xbuf)[s];
            // Stage h for broadcast. In-order DS pipe: following reads see it.
            hbuf[lane] = h;

            float a0 = fmaf(wi0, xq.x, bias);
            float a1 = wi1 * xq.y;
            float a2 = wi2 * xq.z;
            float a3 = 0.0f;

            // Full h vector via 12 b128 + 1 b64 broadcast reads.
            const float4* h4 = (const float4*)hbuf;
            #pragma unroll
            for (int k = 0; k < 12; ++k) {
                float4 hc = h4[k];
                a0 = fmaf(w[4 * k + 0], hc.x, a0);
                a1 = fmaf(w[4 * k + 1], hc.y, a1);
                a2 = fmaf(w[4 * k + 2], hc.z, a2);
                a3 = fmaf(w[4 * k + 3], hc.w, a3);
            }
            float2 ht = ((const float2*)hbuf)[24];   // h[48], h[49]
            a0 = fmaf(w[48], ht.x, a0);
            a1 = fmaf(w[49], ht.y, a1);

            h = fmaxf((a0 + a1) + (a2 + a3), 0.0f);

            // Stash for output projection. Lanes 50-63 duplicate lane 49's value
            // into unused rows (hsT has 64 rows) -- harmless, avoids a branch.
            hsT[lane * HSTR + s] = h;
        }

        // Output projection: lane s computes y[t0+s, 0:3]. Same wave, in-order
        // DS pipe -> step-loop writes above are visible, no barrier needed.
        if (lane < TILE) {
            float y0 = bo0, y1 = bo1, y2 = bo2;
            #pragma unroll
            for (int i = 0; i < HH; ++i) {
                float hv = hsT[i * HSTR + lane];        // stride 51: conflict-free
                float4 wv = ((const float4*)woT)[i];    // broadcast
                y0 = fmaf(wv.x, hv, y0);
                y1 = fmaf(wv.y, hv, y1);
                y2 = fmaf(wv.z, hv, y2);
            }
            float* yp = yb + (size_t)(t0 + lane) * DD;
            yp[0] = y0; yp[1] = y1; yp[2] = y2;
        }
    }
}

extern "C" void kernel_launch(void* const* d_in, const int* in_sizes, int n_in,
                              void* d_out, int out_size, void* d_ws, size_t ws_size,
                              hipStream_t stream) {
    const float* x     = (const float*)d_in[0];
    const float* W_ih  = (const float*)d_in[1];
    const float* W_hh  = (const float*)d_in[2];
    const float* b_ih  = (const float*)d_in[3];
    const float* b_hh  = (const float*)d_in[4];
    const float* W_out = (const float*)d_in[5];
    const float* b_out = (const float*)d_in[6];
    float* out = (float*)d_out;

    rnn_fused_kernel<<<BB, 64, 0, stream>>>(x, W_ih, W_hh, b_ih, b_hh, W_out, b_out, out);
}

// Round 5
// 669.288 us; speedup vs baseline: 1.6042x; 1.6042x over previous
//
#include <hip/hip_runtime.h>

// RNN: h_t = relu(x_t @ W_ih^T + b_ih + b_hh + h_{t-1} @ W_hh^T); y_t = h_t @ W_out^T + b_out
// B=512, T=2000, D=3, H=50.
//
// R5 (= R4 + type fix): MFMA recurrence with ZERO cross-lane feedback. Key identity
// for v_mfma_f32_16x16x16_f16: C/D reg r holds row m = 16*tile + 4*(lane>>4) + r;
// B operand slot j holds k = 16*chunk + 4*(lane>>4) + j. With chunk==tile these
// coincide -> step t's accumulator IS step t+1's B fragment (after lane-local
// relu + cvt_pkrtz pack). The matrix unit does the h broadcast in hardware
// (readlane ~9cyc/val and LDS broadcast ~64cyc/b128 both measured too slow).
//
// Augmented system (64x64 A matrix, per-lane constant):
//   A[m][k]    = W_hh[m][k]        m<50, k<50
//   A[m][50+d] = W_ih[m][d]        m<50, d<3        (x enters as B rows 50..52)
//   A[50+r][k] = W_out[r][k]       r<3,  k<50       (y emerges at rows 50..52, 1-step lag)
//   C-init[m]  = b_ih+b_hh (m<50) | b_out (m=50..52)  -- exact fp32, loop-invariant regs
// 16 batches per wave (N=16), 32 blocks. 2001 iterations (last drains y_1999).

#define TT   2000
#define NB   16
#define XT   16              // x-staging tile (steps); 125 tiles exactly
#define NTILE (TT / XT)

typedef __fp16 half2_t __attribute__((ext_vector_type(2)));
typedef __fp16 half4_t __attribute__((ext_vector_type(4)));
typedef float  f32x4   __attribute__((ext_vector_type(4)));

__device__ __forceinline__ half2_t pk(float a, float b) {
    return __builtin_amdgcn_cvt_pkrtz(a, b);
}

__global__ __launch_bounds__(64) void rnn_mfma_kernel(
    const float* __restrict__ x,      // [B,T,D]
    const float* __restrict__ W_ih,   // [H,D]
    const float* __restrict__ W_hh,   // [H,H]
    const float* __restrict__ b_ih,   // [H]
    const float* __restrict__ b_hh,   // [H]
    const float* __restrict__ W_out,  // [D,H]
    const float* __restrict__ b_out,  // [D]
    float* __restrict__ out)          // [B,T,D]
{
    const int lane = threadIdx.x;
    const int n    = lane & 15;       // batch column
    const int q    = lane >> 4;       // quad group
    const int b0   = blockIdx.x * NB;

    // ---- A fragments (fp16) and bias C-init (fp32), loop-invariant ----
    half4_t A[4][4];
    #pragma unroll
    for (int t = 0; t < 4; ++t) {
        #pragma unroll
        for (int c = 0; c < 4; ++c) {
            const int m = 16 * t + n;
            const int kb = 16 * c + 4 * q;
            half4_t a;
            #pragma unroll
            for (int j = 0; j < 4; ++j) {
                const int k = kb + j;
                float v = 0.0f;
                if (m < 50) {
                    if (k < 50)      v = W_hh[m * 50 + k];
                    else if (k < 53) v = W_ih[m * 3 + (k - 50)];
                } else if (m < 53 && k < 50) {
                    v = W_out[(m - 50) * 50 + k];
                }
                a[j] = (__fp16)v;
            }
            A[t][c] = a;
        }
    }
    f32x4 BIAS[4];
    #pragma unroll
    for (int t = 0; t < 4; ++t) {
        #pragma unroll
        for (int r = 0; r < 4; ++r) {
            const int m = 16 * t + 4 * q + r;
            float v = 0.0f;
            if (m < 50)      v = b_ih[m] + b_hh[m];
            else if (m < 53) v = b_out[m - 50];
            BIAS[t][r] = v;
        }
    }

    // ---- x staging: double-buffered LDS, prefetch next tile into registers ----
    // Staging lane mapping: bl = lane>>2 (batch), c4 = lane&3 (quarter of tile).
    // Lane holds x[b0+bl, t0 + 4*c4 .. +3, 0:3] = 12 floats = 3 float4 (contiguous).
    __shared__ float4 xbuf[2 * XT * 16];   // [buf][step][batch] -> {x0,x1,x2,pad}

    const int bl = lane >> 2;
    const int c4 = lane & 3;
    const float4* xg = (const float4*)(x + (size_t)(b0 + bl) * (TT * 3)) + c4 * 3;

    float4 f0, f1, f2;
    { // issue loads for tile 0
        const float4* p = xg;           // tile 0: float4 idx c4*3 + {0,1,2}
        f0 = p[0]; f1 = p[1]; f2 = p[2];
    }

    f32x4 acc0 = {0,0,0,0}, acc1 = {0,0,0,0}, acc2 = {0,0,0,0}, acc3 = {0,0,0,0};
    float* const ybase = out + (size_t)(b0 + n) * (TT * 3);

    for (int t = 0; t <= TT; ++t) {
        // ---- staging at tile boundaries ----
        if ((t & (XT - 1)) == 0 && t < TT) {
            const int k = t >> 4;                       // tile being entered
            const int base = ((k & 1) * XT + 4 * c4) * 16 + bl;
            float4 w0, w1, w2, w3;
            w0.x = f0.x; w0.y = f0.y; w0.z = f0.z; w0.w = 0.0f;
            w1.x = f0.w; w1.y = f1.x; w1.z = f1.y; w1.w = 0.0f;
            w2.x = f1.z; w2.y = f1.w; w2.z = f2.x; w2.w = 0.0f;
            w3.x = f2.y; w3.y = f2.z; w3.z = f2.w; w3.w = 0.0f;
            xbuf[base + 0 * 16] = w0;
            xbuf[base + 1 * 16] = w1;
            xbuf[base + 2 * 16] = w2;
            xbuf[base + 3 * 16] = w3;
            if (k + 1 < NTILE) {                        // prefetch next tile
                const float4* p = xg + (size_t)(k + 1) * 12;
                f0 = p[0]; f1 = p[1]; f2 = p[2];
            }
        }

        // ---- x triple for this step (LDS read; 16 distinct addrs, 4-way bcast) ----
        float4 xt;
        if (t < TT) xt = xbuf[((t & 31) << 4) + n];
        else        { xt.x = 0.0f; xt.y = 0.0f; xt.z = 0.0f; xt.w = 0.0f; }

        // ---- relu of previous step's accumulators (lane-local) ----
        f32x4 r0, r1, r2, r3;
        #pragma unroll
        for (int i = 0; i < 4; ++i) {
            r0[i] = fmaxf(acc0[i], 0.0f);
            r1[i] = fmaxf(acc1[i], 0.0f);
            r2[i] = fmaxf(acc2[i], 0.0f);
            r3[i] = fmaxf(acc3[i], 0.0f);
        }

        // ---- pack B fragments (lane-local; chunk==tile identity) ----
        half2_t p00 = pk(r0[0], r0[1]), p01 = pk(r0[2], r0[3]);
        half2_t p10 = pk(r1[0], r1[1]), p11 = pk(r1[2], r1[3]);
        half2_t p20 = pk(r2[0], r2[1]), p21 = pk(r2[2], r2[3]);
        half2_t hh  = pk(r3[0], r3[1]);           // h48,h49 (valid for q==0)
        half2_t x01 = pk(xt.x, xt.y);
        half2_t x2z = pk(xt.z, 0.0f);
        const half2_t hz = {(__fp16)0.0f, (__fp16)0.0f};

        half2_t b3a = (q == 0) ? hh  : ((q == 1) ? x2z : hz);  // k=48..49 | 52..53
        half2_t b3b = (q == 0) ? x01 : hz;                     // k=50..51

        half4_t B0 = __builtin_shufflevector(p00, p01, 0, 1, 2, 3);
        half4_t B1 = __builtin_shufflevector(p10, p11, 0, 1, 2, 3);
        half4_t B2 = __builtin_shufflevector(p20, p21, 0, 1, 2, 3);
        half4_t B3 = __builtin_shufflevector(b3a, b3b, 0, 1, 2, 3);

        // ---- 16 MFMAs: 4 M-tiles x 4 K-chunks, bias as C-init of chunk 0 ----
        acc0 = __builtin_amdgcn_mfma_f32_16x16x16f16(A[0][0], B0, BIAS[0], 0, 0, 0);
        acc1 = __builtin_amdgcn_mfma_f32_16x16x16f16(A[1][0], B0, BIAS[1], 0, 0, 0);
        acc2 = __builtin_amdgcn_mfma_f32_16x16x16f16(A[2][0], B0, BIAS[2], 0, 0, 0);
        acc3 = __builtin_amdgcn_mfma_f32_16x16x16f16(A[3][0], B0, BIAS[3], 0, 0, 0);
        acc0 = __builtin_amdgcn_mfma_f32_16x16x16f16(A[0][1], B1, acc0, 0, 0, 0);
        acc1 = __builtin_amdgcn_mfma_f32_16x16x16f16(A[1][1], B1, acc1, 0, 0, 0);
        acc2 = __builtin_amdgcn_mfma_f32_16x16x16f16(A[2][1], B1, acc2, 0, 0, 0);
        acc3 = __builtin_amdgcn_mfma_f32_16x16x16f16(A[3][1], B1, acc3, 0, 0, 0);
        acc0 = __builtin_amdgcn_mfma_f32_16x16x16f16(A[0][2], B2, acc0, 0, 0, 0);
        acc1 = __builtin_amdgcn_mfma_f32_16x16x16f16(A[1][2], B2, acc1, 0, 0, 0);
        acc2 = __builtin_amdgcn_mfma_f32_16x16x16f16(A[2][2], B2, acc2, 0, 0, 0);
        acc3 = __builtin_amdgcn_mfma_f32_16x16x16f16(A[3][2], B2, acc3, 0, 0, 0);
        acc0 = __builtin_amdgcn_mfma_f32_16x16x16f16(A[0][3], B3, acc0, 0, 0, 0);
        acc1 = __builtin_amdgcn_mfma_f32_16x16x16f16(A[1][3], B3, acc1, 0, 0, 0);
        acc2 = __builtin_amdgcn_mfma_f32_16x16x16f16(A[2][3], B3, acc2, 0, 0, 0);
        acc3 = __builtin_amdgcn_mfma_f32_16x16x16f16(A[3][3], B3, acc3, 0, 0, 0);

        // ---- store y_{t-1} (rows 50..52 of new acc3, pre-relu) ----
        if (t >= 1) {
            float* yp = ybase + (size_t)(t - 1) * 3;
            if (q == 0)      { yp[0] = acc3[2]; yp[1] = acc3[3]; }
            else if (q == 1) { yp[2] = acc3[0]; }
        }
    }
}

extern "C" void kernel_launch(void* const* d_in, const int* in_sizes, int n_in,
                              void* d_out, int out_size, void* d_ws, size_t ws_size,
                              hipStream_t stream) {
    const float* x     = (const float*)d_in[0];
    const float* W_ih  = (const float*)d_in[1];
    const float* W_hh  = (const float*)d_in[2];
    const float* b_ih  = (const float*)d_in[3];
    const float* b_hh  = (const float*)d_in[4];
    const float* W_out = (const float*)d_in[5];
    const float* b_out = (const float*)d_in[6];
    float* out = (float*)d_out;

    rnn_mfma_kernel<<<512 / NB, 64, 0, stream>>>(x, W_ih, W_hh, b_ih, b_hh, W_out, b_out, out);
}

// Round 6
// 662.280 us; speedup vs baseline: 1.6212x; 1.0106x over previous
//
#include <hip/hip_runtime.h>

// RNN: h_t = relu(x_t @ W_ih^T + b_ih + b_hh + h_{t-1} @ W_hh^T); y_t = h_t @ W_out^T + b_out
// B=512, T=2000, D=3, H=50.
//
// R6: same verified MFMA recurrence as R5 (augmented 64x64 system, 16x16x16 f16,
// C/D-layout == B-layout identity -> zero cross-lane feedback), restructured for
// latency: (1) x via per-lane global dwordx3 register pipeline (depth 3, no LDS);
// (2) MFMA chains depth 2 (u/v pairs + v_pk_add) instead of depth 4;
// (3) branch-free y stash to LDS, coalesced flush every 16 steps;
// (4) fully unrolled 16-step tiles so the compiler pipelines across steps.
//
// Augmented system:
//   A[m][k]    = W_hh[m][k]        m<50, k<50
//   A[m][50+d] = W_ih[m][d]        m<50, d<3
//   A[50+r][k] = W_out[r][k]       r<3,  k<50   (y emerges at rows 50..52, 1-step lag)
//   C-init     = b_ih+b_hh | b_out
// 16 batches/wave, 32 blocks. Iterations i=0..2000; iteration i stashes y_{i-1}.

#define TT 2000
#define NB 16

typedef __fp16 half2_t __attribute__((ext_vector_type(2)));
typedef __fp16 half4_t __attribute__((ext_vector_type(4)));
typedef float  f32x4   __attribute__((ext_vector_type(4)));

__device__ __forceinline__ half2_t pk(float a, float b) {
    return __builtin_amdgcn_cvt_pkrtz(a, b);
}

__global__ __launch_bounds__(64) void rnn_mfma_kernel(
    const float* __restrict__ x,      // [B,T,D]
    const float* __restrict__ W_ih,   // [H,D]
    const float* __restrict__ W_hh,   // [H,H]
    const float* __restrict__ b_ih,   // [H]
    const float* __restrict__ b_hh,   // [H]
    const float* __restrict__ W_out,  // [D,H]
    const float* __restrict__ b_out,  // [D]
    float* __restrict__ out)          // [B,T,D]
{
    const int lane = threadIdx.x;
    const int n    = lane & 15;       // batch column
    const int q    = lane >> 4;       // quad group
    const int b0   = blockIdx.x * NB;

    // ---- A fragments (fp16) and bias C-init (fp32), loop-invariant ----
    half4_t A[4][4];
    #pragma unroll
    for (int t = 0; t < 4; ++t) {
        #pragma unroll
        for (int c = 0; c < 4; ++c) {
            const int m = 16 * t + n;
            const int kb = 16 * c + 4 * q;
            half4_t a;
            #pragma unroll
            for (int j = 0; j < 4; ++j) {
                const int k = kb + j;
                float v = 0.0f;
                if (m < 50) {
                    if (k < 50)      v = W_hh[m * 50 + k];
                    else if (k < 53) v = W_ih[m * 3 + (k - 50)];
                } else if (m < 53 && k < 50) {
                    v = W_out[(m - 50) * 50 + k];
                }
                a[j] = (__fp16)v;
            }
            A[t][c] = a;
        }
    }
    f32x4 BIAS[4];
    #pragma unroll
    for (int t = 0; t < 4; ++t) {
        #pragma unroll
        for (int r = 0; r < 4; ++r) {
            const int m = 16 * t + 4 * q + r;
            float v = 0.0f;
            if (m < 50)      v = b_ih[m] + b_hh[m];
            else if (m < 53) v = b_out[m - 50];
            BIAS[t][r] = v;
        }
    }

    // y stash: [16 steps][16 batches][4 floats] + 64-float dump row for q>=2 lanes
    __shared__ float ybuf[16 * 16 * 4 + 64];

    // ---- x register pipeline: per-lane x[b0+n][i][0:3], prefetch depth 3 ----
    const float* xp = x + (size_t)(b0 + n) * (TT * 3);
    float3 xc  = *(const float3*)(xp + 0);
    float3 xn1 = *(const float3*)(xp + 3);
    float3 xn2 = *(const float3*)(xp + 6);

    f32x4 acc0 = {0,0,0,0}, acc1 = {0,0,0,0}, acc2 = {0,0,0,0}, acc3 = {0,0,0,0};
    const f32x4 z4 = {0,0,0,0};

    auto body = [&](int i) {
        // relu of previous accumulators (lane-local)
        f32x4 r0, r1, r2, r3;
        #pragma unroll
        for (int e = 0; e < 4; ++e) {
            r0[e] = fmaxf(acc0[e], 0.0f);
            r1[e] = fmaxf(acc1[e], 0.0f);
            r2[e] = fmaxf(acc2[e], 0.0f);
            r3[e] = fmaxf(acc3[e], 0.0f);
        }
        // pack B fragments (chunk==tile identity)
        half2_t p00 = pk(r0[0], r0[1]), p01 = pk(r0[2], r0[3]);
        half2_t p10 = pk(r1[0], r1[1]), p11 = pk(r1[2], r1[3]);
        half2_t p20 = pk(r2[0], r2[1]), p21 = pk(r2[2], r2[3]);
        half2_t hh  = pk(r3[0], r3[1]);          // h48,h49 (q==0)
        half2_t x01 = pk(xc.x, xc.y);
        half2_t x2z = pk(xc.z, 0.0f);
        const half2_t hz = {(__fp16)0.0f, (__fp16)0.0f};
        half2_t b3a = (q == 0) ? hh  : ((q == 1) ? x2z : hz);  // k=48..49 | 52..53
        half2_t b3b = (q == 0) ? x01 : hz;                     // k=50..51
        half4_t B0 = __builtin_shufflevector(p00, p01, 0, 1, 2, 3);
        half4_t B1 = __builtin_shufflevector(p10, p11, 0, 1, 2, 3);
        half4_t B2 = __builtin_shufflevector(p20, p21, 0, 1, 2, 3);
        half4_t B3 = __builtin_shufflevector(b3a, b3b, 0, 1, 2, 3);

        // 16 MFMAs as two depth-2 chains per M-tile; level-1 all independent
        f32x4 u0 = __builtin_amdgcn_mfma_f32_16x16x16f16(A[0][0], B0, BIAS[0], 0, 0, 0);
        f32x4 u1 = __builtin_amdgcn_mfma_f32_16x16x16f16(A[1][0], B0, BIAS[1], 0, 0, 0);
        f32x4 u2 = __builtin_amdgcn_mfma_f32_16x16x16f16(A[2][0], B0, BIAS[2], 0, 0, 0);
        f32x4 u3 = __builtin_amdgcn_mfma_f32_16x16x16f16(A[3][0], B0, BIAS[3], 0, 0, 0);
        f32x4 v0 = __builtin_amdgcn_mfma_f32_16x16x16f16(A[0][2], B2, z4, 0, 0, 0);
        f32x4 v1 = __builtin_amdgcn_mfma_f32_16x16x16f16(A[1][2], B2, z4, 0, 0, 0);
        f32x4 v2 = __builtin_amdgcn_mfma_f32_16x16x16f16(A[2][2], B2, z4, 0, 0, 0);
        f32x4 v3 = __builtin_amdgcn_mfma_f32_16x16x16f16(A[3][2], B2, z4, 0, 0, 0);
        u0 = __builtin_amdgcn_mfma_f32_16x16x16f16(A[0][1], B1, u0, 0, 0, 0);
        u1 = __builtin_amdgcn_mfma_f32_16x16x16f16(A[1][1], B1, u1, 0, 0, 0);
        u2 = __builtin_amdgcn_mfma_f32_16x16x16f16(A[2][1], B1, u2, 0, 0, 0);
        u3 = __builtin_amdgcn_mfma_f32_16x16x16f16(A[3][1], B1, u3, 0, 0, 0);
        v0 = __builtin_amdgcn_mfma_f32_16x16x16f16(A[0][3], B3, v0, 0, 0, 0);
        v1 = __builtin_amdgcn_mfma_f32_16x16x16f16(A[1][3], B3, v1, 0, 0, 0);
        v2 = __builtin_amdgcn_mfma_f32_16x16x16f16(A[2][3], B3, v2, 0, 0, 0);
        v3 = __builtin_amdgcn_mfma_f32_16x16x16f16(A[3][3], B3, v3, 0, 0, 0);
        acc0 = u0 + v0;
        acc1 = u1 + v1;
        acc2 = u2 + v2;
        acc3 = u3 + v3;

        // stash y_{i-1} (rows 50..52 live in acc3), branch-free
        const int s = (i - 1) & 15;
        float w0 = (q == 0) ? acc3[2] : acc3[0];
        float w1 = (q == 0) ? acc3[3] : 0.0f;
        int base = (q < 2) ? ((s * 16 + n) * 4 + 2 * q) : (1024 + (lane & 31) * 2);
        ybuf[base]     = w0;
        ybuf[base + 1] = w1;

        // rotate x pipeline (prefetch depth 3; clamp tail, harmless reuse)
        xc = xn1; xn1 = xn2;
        int tn = i + 3; if (tn > TT - 1) tn = TT - 1;
        xn2 = *(const float3*)(xp + 3 * tn);
    };

    body(0);   // computes acc(0); stash goes to slot 15, overwritten before flush

    const int bl = lane >> 2;   // flush lane mapping: batch
    const int c4 = lane & 3;    // quarter of the 16-step tile

    for (int tile = 0; tile < TT / 16; ++tile) {
        #pragma unroll
        for (int s2 = 0; s2 < 16; ++s2) body(tile * 16 + s2 + 1);

        // flush y_{tile*16 .. +15}: coalesced dwordx4 stores
        const f32x4* yv = (const f32x4*)ybuf;
        f32x4 a0 = yv[(4 * c4 + 0) * 16 + bl];
        f32x4 a1 = yv[(4 * c4 + 1) * 16 + bl];
        f32x4 a2 = yv[(4 * c4 + 2) * 16 + bl];
        f32x4 a3 = yv[(4 * c4 + 3) * 16 + bl];
        float* gp = out + (size_t)(b0 + bl) * (TT * 3) + (size_t)(tile * 16 + 4 * c4) * 3;
        float4 s0 = {a0[0], a0[1], a0[2], a1[0]};
        float4 s1 = {a1[1], a1[2], a2[0], a2[1]};
        float4 s2 = {a2[2], a3[0], a3[1], a3[2]};
        *(float4*)(gp + 0) = s0;
        *(float4*)(gp + 4) = s1;
        *(float4*)(gp + 8) = s2;
    }
}

extern "C" void kernel_launch(void* const* d_in, const int* in_sizes, int n_in,
                              void* d_out, int out_size, void* d_ws, size_t ws_size,
                              hipStream_t stream) {
    const float* x     = (const float*)d_in[0];
    const float* W_ih  = (const float*)d_in[1];
    const float* W_hh  = (const float*)d_in[2];
    const float* b_ih  = (const float*)d_in[3];
    const float* b_hh  = (const float*)d_in[4];
    const float* W_out = (const float*)d_in[5];
    const float* b_out = (const float*)d_in[6];
    float* out = (float*)d_out;

    rnn_mfma_kernel<<<512 / NB, 64, 0, stream>>>(x, W_ih, W_hh, b_ih, b_hh, W_out, b_out, out);
}